// Round 7
// baseline (404.634 us; speedup 1.0000x reference)
//
#include <hip/hip_runtime.h>
#include <hip/hip_bf16.h>

#define B_SZ 4
#define NHEADS 16
#define T_SZ 2048
#define DE 1024
#define DH 64
#define BH (B_SZ*NHEADS)
#define SCL 0.18033688011112042f  /* 0.125 * log2(e) */

typedef __attribute__((ext_vector_type(8))) short short8;   // 8 bf16 = 4 VGPRs
typedef __attribute__((ext_vector_type(4))) float float4v;
typedef __attribute__((ext_vector_type(16))) float f32x16;
typedef __attribute__((ext_vector_type(2))) unsigned int uint2v;
typedef __attribute__((ext_vector_type(4))) unsigned int uint4v;

__device__ __forceinline__ short f2bf(float f) {
    __hip_bfloat16 h = __float2bfloat16(f);
    return *reinterpret_cast<short*>(&h);
}
__device__ __forceinline__ unsigned int pack_bf2(float a, float b) {
    float2 f; f.x = a; f.y = b;
    __hip_bfloat162 h = __float22bfloat162_rn(f);
    return *reinterpret_cast<unsigned int*>(&h);
}
__device__ __forceinline__ float4v zero4() {
    float4v z = {0.f, 0.f, 0.f, 0.f};
    return z;
}
// XOR-swizzled stride-64 LDS tile (qkv_k staging). g is the LOGICAL 8-element
// column group; physical slot is g ^ (row & 7).
__device__ __forceinline__ int swz(int row, int g) {
    return row * 64 + (((g) ^ (row & 7)) << 3);
}
// async 16B global -> LDS (linear dest: wave-uniform base + lane*16)
__device__ __forceinline__ void gl_lds16(const short* g, short* l) {
    __builtin_amdgcn_global_load_lds(
        (const __attribute__((address_space(1))) void*)g,
        (__attribute__((address_space(3))) void*)l, 16, 0, 0);
}

// ---- transpose+downcast: fp32 src[R][C] -> bf16 dst[C][R], batched over z ---
__global__ __launch_bounds__(256) void transpose_k(const float* __restrict__ src,
                                                   short* __restrict__ dst,
                                                   int R, int C) {
    __shared__ __align__(16) short tile[64 * 65];
    int c0 = blockIdx.x * 64, r0 = blockIdx.y * 64;
    src += (size_t)blockIdx.z * R * C;
    dst += (size_t)blockIdx.z * R * C;
    int tid = threadIdx.x;
#pragma unroll
    for (int it = 0; it < 16; ++it) {
        int idx = it * 256 + tid;
        int rr = idx >> 6, cc = idx & 63;
        tile[cc * 65 + rr] = f2bf(src[(size_t)(r0 + rr) * C + c0 + cc]);
    }
    __syncthreads();
#pragma unroll
    for (int it = 0; it < 16; ++it) {
        int idx = it * 256 + tid;
        int cc = idx >> 6, rr = idx & 63;
        dst[(size_t)(c0 + cc) * R + r0 + rr] = tile[cc * 65 + rr];
    }
}

// ------ QKV projection + q/k norm: M=128 x N=128 (2 heads), 2-phase dbuf -----
// Grid (64, 24) = 1536 blocks = exactly 3 rounds at 2 blocks/CU (64 KB LDS).
// K-loop: STAGE(t+1) issued BEFORE COMPUTE(t), ONE __syncthreads per K-step.
// XT: [b][t][d] bf16 ; WT: [n][h*64+e][d] bf16
// Qw (pre-scaled by SCL), Kw: [bh][t][e] ; Vt: [bh][e][t]
__global__ __launch_bounds__(256, 2) void qkv_k(const short* __restrict__ XT,
                                                const short* __restrict__ WT,
                                                short* __restrict__ Qw,
                                                short* __restrict__ Kw,
                                                short* __restrict__ Vt) {
    __shared__ __align__(16) short ldsA[2][128 * 64];   // 2 x 16 KB, swizzled
    __shared__ __align__(16) short ldsB[2][128 * 64];   // 2 x 16 KB, swizzled
    int b  = blockIdx.x >> 4;                        // grid.x = 64: same-A blocks
    int t0 = (blockIdx.x & 15) * 128;                //   share XCD (x mod 8 const in y)
    int n  = blockIdx.y >> 3;
    int h0 = (blockIdx.y & 7) * 2;                   // 2 heads per block
    int tid = threadIdx.x, wave = tid >> 6, lane = tid & 63;
    int l15 = lane & 15, quad = lane >> 4;
    int wr = wave >> 1, wc = wave & 1;               // 2x2 wave grid

    const short* Arow = XT + ((size_t)b * T_SZ + t0) * DE;
    const short* Brow = WT + ((size_t)n * 1024 + h0 * 64) * DE;

    // per-lane pre-swizzle for global_load_lds staging
    int rA = lane >> 3;                   // row within the wave's 8-row stripe
    int gl = (lane & 7) ^ rA;             // logical column group for this slot

    float4v acc[4][4];
#pragma unroll
    for (int mm = 0; mm < 4; ++mm)
#pragma unroll
        for (int j = 0; j < 4; ++j) acc[mm][j] = zero4();

    auto STAGE = [&](short* La, short* Lb, int k0) {
#pragma unroll
        for (int it = 0; it < 4; ++it) {       // A,B: 128 rows, 8 rows/wave/issue
            int rowbase = it * 32 + wave * 8;
            gl_lds16(&Arow[(size_t)(rowbase + rA) * DE + k0 + gl * 8],
                     &La[(it * 256 + wave * 64) * 8]);
            gl_lds16(&Brow[(size_t)(rowbase + rA) * DE + k0 + gl * 8],
                     &Lb[(it * 256 + wave * 64) * 8]);
        }
    };
    auto COMPUTE = [&](const short* La, const short* Lb) {
#pragma unroll
        for (int ks = 0; ks < 2; ++ks) {
            short8 af[4], bf[4];
#pragma unroll
            for (int mm = 0; mm < 4; ++mm)
                af[mm] = *(const short8*)&La[swz(64 * wr + 16 * mm + l15, 4 * ks + quad)];
#pragma unroll
            for (int j = 0; j < 4; ++j)
                bf[j] = *(const short8*)&Lb[swz(64 * wc + 16 * j + l15, 4 * ks + quad)];
#pragma unroll
            for (int mm = 0; mm < 4; ++mm)
#pragma unroll
                for (int j = 0; j < 4; ++j)
                    acc[mm][j] = __builtin_amdgcn_mfma_f32_16x16x32_bf16(af[mm], bf[j], acc[mm][j], 0, 0, 0);
        }
    };

    STAGE(ldsA[0], ldsB[0], 0);
    __syncthreads();
    for (int k0 = 0; k0 < DE; k0 += 128) {     // 8 iters, 2 K-steps each
        STAGE(ldsA[1], ldsB[1], k0 + 64);      // k0+64 <= 960 always in-range
        COMPUTE(ldsA[0], ldsB[0]);
        __syncthreads();                       // drains prefetch + my ds_reads
        if (k0 + 128 < DE)
            STAGE(ldsA[0], ldsB[0], k0 + 128);
        COMPUTE(ldsA[1], ldsB[1]);
        __syncthreads();
    }

    // epilogue: wave owns one head (wc); per 16-row subtile mm
    int h = h0 + wc;
    int bh = b * NHEADS + h;
#pragma unroll
    for (int mm = 0; mm < 4; ++mm) {
        int tbase = t0 + 64 * wr + 16 * mm;
        if (n < 2) {
            float oscale = (n == 0) ? SCL : 1.0f;
            float mu[4], inv[4];
#pragma unroll
            for (int r = 0; r < 4; ++r) {
                float s1 = 0.f, s2 = 0.f;
#pragma unroll
                for (int jj = 0; jj < 4; ++jj) {
                    float v = acc[mm][jj][r];
                    s1 += v; s2 += v * v;
                }
                for (int sh = 1; sh < 16; sh <<= 1) {
                    s1 += __shfl_xor(s1, sh, 64);
                    s2 += __shfl_xor(s2, sh, 64);
                }
                mu[r] = s1 * (1.0f / 64.0f);
                float var = (s2 - 64.0f * mu[r] * mu[r]) * (1.0f / 63.0f);
                var = fmaxf(var, 0.0f);
                inv[r] = oscale / (sqrtf(var) + 1e-5f);
            }
            short* dst = (n == 0 ? Qw : Kw) + (size_t)bh * T_SZ * DH;
#pragma unroll
            for (int r = 0; r < 4; ++r) {
                int t = tbase + quad * 4 + r;
#pragma unroll
                for (int jj = 0; jj < 4; ++jj) {
                    float v = (acc[mm][jj][r] - mu[r]) * inv[r];
                    dst[(size_t)t * DH + 16 * jj + l15] = f2bf(v);
                }
            }
        } else {
#pragma unroll
            for (int r = 0; r < 4; ++r) {
                int t = tbase + quad * 4 + r;
#pragma unroll
                for (int jj = 0; jj < 4; ++jj) {
                    Vt[((size_t)bh * DH + 16 * jj + l15) * T_SZ + t] =
                        f2bf(acc[mm][jj][r]);
                }
            }
        }
    }
}

// -------- flash attention: 32x32 MFMA, P in-register, NO LDS STAGING --------
// Rounds 2-6 post-mortem: five structurally different staged versions all ran
// ~94.5 us. The invariant was the staging scaffolding itself: ds_write ->
// barrier -> ds_read phase-locks all waves (LDS ~45% + VALU ~50% phases never
// overlap across waves) and pays LDS round-trip + 4-way fragment-read
// conflicts (8.4M) for K/V data that has NO block-level reuse and L2-fits
// (8 bh x 512 KB = 4 MB per XCD). Guide m169/m177: stage only when data
// doesn't cache-fit; dropping staging was the single biggest attn lever.
// This version reads K/V fragments DIRECTLY from global (L1/L2-served) at the
// exact per-lane addresses the swizzled ds_reads used (same refcheck-proven
// fragment mapping). No barriers in the loop at all: waves free-run, pipes
// interleave across 16 waves/CU. Softmax+PV interleaved per ss-half to keep
// VGPR ~110 (fits 128 @ 4 blocks/CU).
// Grid (bh=64, tq=16) = 1024 blocks = 4 blocks/CU; same-bh blocks share an
// XCD (wgid mod 8 = bh mod 8) so K/V walks hit the same L2.
// Qw (pre-scaled), Kw: [bh][t][e] ; Vt: [bh][e][t]  (bf16) ; out: fp32 [b][h*64+e][t]
// |q.k*SCL| <= 11.4 -> exp2 never overflows; no max subtraction needed.
__global__ __launch_bounds__(256, 4) void attn_k(const short* __restrict__ Qw,
                                                 const short* __restrict__ Kw,
                                                 const short* __restrict__ Vt,
                                                 float* __restrict__ out) {
    __shared__ float ldsL[4][32];               // per-wave rinv broadcast only

    int bh = blockIdx.x;
    int t0 = blockIdx.y * 128;
    int b = bh >> 4, h = bh & 15;
    int tid = threadIdx.x, wave = tid >> 6, lane = tid & 63;
    int l31 = lane & 31, b5 = lane >> 5;
    int tw = t0 + 32 * wave;                    // this wave's 32 q-rows

    const short* Qp = Qw + (size_t)bh * T_SZ * DH;
    const short* Kp = Kw + (size_t)bh * T_SZ * DH;
    const short* Vp = Vt + (size_t)bh * DH * T_SZ;

    // Q B-frags: qf[kk]: t = tw+l31, k = 16*kk+8*b5+e
    short8 qf[4];
#pragma unroll
    for (int kk = 0; kk < 4; ++kk)
        qf[kk] = *(const short8*)&Qp[(size_t)(tw + l31) * DH + 16 * kk + 8 * b5];

    f32x16 o0 = (f32x16)0.0f, o1 = (f32x16)0.0f;  // [etile]; C: row=t(regs), col=e(lane)
    float ol = 0.f;                    // per-lane partial l(t = tw+l31), own b5-half

    for (int s0 = 0; s0 < T_SZ; s0 += 64) {
#pragma unroll
        for (int ss = 0; ss < 2; ++ss) {
            // QK^T: K A-frag direct from global: s = s0+32ss+l31, k = 16kk+8b5+e
            f32x16 z = (f32x16)0.0f;
#pragma unroll
            for (int kk = 0; kk < 4; ++kk) {
                short8 ak = *(const short8*)&Kp[(size_t)(s0 + 32 * ss + l31) * DH + 16 * kk + 8 * b5];
                z = __builtin_amdgcn_mfma_f32_32x32x16_bf16(ak, qf[kk], z, 0, 0, 0);
            }
            // exp2 + pack: z[r] = S^T[s_loc = 32ss+(r&3)+8*(r>>2)+4b5][t = tw+l31]
            uint2v u[4];   // [g]: dw0 = P(s = 32ss+8g+4b5+{0,1}), dw1 = {2,3}
#pragma unroll
            for (int g = 0; g < 4; ++g) {
                float p0 = __builtin_amdgcn_exp2f(z[4 * g + 0]);
                float p1 = __builtin_amdgcn_exp2f(z[4 * g + 1]);
                float p2 = __builtin_amdgcn_exp2f(z[4 * g + 2]);
                float p3 = __builtin_amdgcn_exp2f(z[4 * g + 3]);
                ol += (p0 + p1) + (p2 + p3);
                u[g].x = pack_bf2(p0, p1);
                u[g].y = pack_bf2(p2, p3);
            }
            // PV for this ss-half: kks = 2ss+kkh; pf = P[t=own col][s=16kks+8b5..+7]
            // via permlane32_swap (verified layout, rounds 5-6).
#pragma unroll
            for (int kkh = 0; kkh < 2; ++kkh) {
                const int ga = 2 * kkh;
                unsigned a0 = u[ga].x,     a1 = u[ga].y;
                unsigned b0 = u[ga + 1].x, b1 = u[ga + 1].y;
                asm("v_permlane32_swap_b32 %0, %1" : "+v"(a0), "+v"(b0));
                asm("v_permlane32_swap_b32 %0, %1" : "+v"(a1), "+v"(b1));
                uint4v up; up.x = a0; up.y = a1; up.z = b0; up.w = b1;
                short8 pf = *(short8*)&up;
                // V B-frags direct from global: e = 32et+l31, s = s0+16kks+8b5+e'
                const int sc = s0 + 16 * (2 * ss + kkh) + 8 * b5;
                short8 v0 = *(const short8*)&Vp[(size_t)l31 * T_SZ + sc];
                short8 v1 = *(const short8*)&Vp[(size_t)(32 + l31) * T_SZ + sc];
                o0 = __builtin_amdgcn_mfma_f32_32x32x16_bf16(pf, v0, o0, 0, 0, 0);
                o1 = __builtin_amdgcn_mfma_f32_32x32x16_bf16(pf, v1, o1, 0, 0, 0);
            }
        }
    }

    // l(t) = ol + partner-half; broadcast rinv via wave-private LDS row
    // (within-wave ds write->read; compiler inserts lgkmcnt — no barrier needed)
    {
        float l = ol + __shfl_xor(ol, 32, 64);
        if (lane < 32) ldsL[wave][lane] = 1.0f / l;
    }

    // epilogue: o reg 4g+i is t = tw+8g+4b5+i, e = 32et+l31 -> float4 direct
#pragma unroll
    for (int g = 0; g < 4; ++g) {
        float4v ri = *(const float4v*)&ldsL[wave][8 * g + 4 * b5];
        float4v ov;
#pragma unroll
        for (int i = 0; i < 4; ++i) ov[i] = o0[4 * g + i] * ri[i];
        *(float4v*)&out[(size_t)(b * DE + h * DH + l31) * T_SZ
                        + tw + 8 * g + 4 * b5] = ov;
#pragma unroll
        for (int i = 0; i < 4; ++i) ov[i] = o1[4 * g + i] * ri[i];
        *(float4v*)&out[(size_t)(b * DE + h * DH + 32 + l31) * T_SZ
                        + tw + 8 * g + 4 * b5] = ov;
    }
}

extern "C" void kernel_launch(void* const* d_in, const int* in_sizes, int n_in,
                              void* d_out, int out_size, void* d_ws, size_t ws_size,
                              hipStream_t stream) {
    const float* x = (const float*)d_in[0];   // fp32 [B][D][T]
    const float* w = (const float*)d_in[1];   // fp32 [3][H][D][dh]
    float* out = (float*)d_out;               // fp32 [B][D][T]
    char* ws = (char*)d_ws;

    const size_t XT_BYTES = (size_t)B_SZ * T_SZ * DE * 2;       // 16.8 MB (bf16)
    const size_t WT_BYTES = (size_t)3 * NHEADS * DH * DE * 2;   // 6.3 MB
    const size_t QKV_BYTES = (size_t)BH * T_SZ * DH * 2;        // 16.8 MB each

    short* XT = (short*)(ws);
    short* WT = (short*)(ws + XT_BYTES);
    short* Qw = (short*)(ws + XT_BYTES + WT_BYTES);
    short* Kw = (short*)(ws + XT_BYTES + WT_BYTES + QKV_BYTES);
    short* Vt = (short*)(ws + XT_BYTES + WT_BYTES + 2 * QKV_BYTES);

    // x: per-b fp32 [D][T] -> bf16 XT [T][D]
    transpose_k<<<dim3(T_SZ / 64, DE / 64, B_SZ), 256, 0, stream>>>(x, XT, DE, T_SZ);
    // w: per-nh fp32 [D][dh] -> bf16 WT [nh][e][D]
    transpose_k<<<dim3(1, DE / 64, 3 * NHEADS), 256, 0, stream>>>(w, WT, DE, DH);
    qkv_k<<<dim3(64, 24), 256, 0, stream>>>(XT, WT, Qw, Kw, Vt);
    attn_k<<<dim3(BH, T_SZ / 128), 256, 0, stream>>>(Qw, Kw, Vt, out);
}

// Round 8
// 243.666 us; speedup vs baseline: 1.6606x; 1.6606x over previous
//
#include <hip/hip_runtime.h>
#include <hip/hip_bf16.h>

#define B_SZ 4
#define NHEADS 16
#define T_SZ 2048
#define DE 1024
#define DH 64
#define BH (B_SZ*NHEADS)
#define SCL 0.18033688011112042f  /* 0.125 * log2(e) */

typedef __attribute__((ext_vector_type(8))) short short8;   // 8 bf16 = 4 VGPRs
typedef __attribute__((ext_vector_type(4))) float float4v;
typedef __attribute__((ext_vector_type(16))) float f32x16;
typedef __attribute__((ext_vector_type(2))) unsigned int uint2v;
typedef __attribute__((ext_vector_type(4))) unsigned int uint4v;

__device__ __forceinline__ short f2bf(float f) {
    __hip_bfloat16 h = __float2bfloat16(f);
    return *reinterpret_cast<short*>(&h);
}
__device__ __forceinline__ float4v zero4() {
    float4v z = {0.f, 0.f, 0.f, 0.f};
    return z;
}
// single-instruction RNE pack: dst.lo = bf16(a), dst.hi = bf16(b)
// (__float22bfloat162_rn is software bias-add rounding ~5 ops/value; no builtin
//  for v_cvt_pk_bf16_f32 on gfx950 — guide m240/T12)
__device__ __forceinline__ unsigned int cvt_pk_bf16(float a, float b) {
    unsigned int r;
    asm("v_cvt_pk_bf16_f32 %0, %1, %2" : "=v"(r) : "v"(a), "v"(b));
    return r;
}
// XOR-swizzled stride-64 LDS tile. g is the LOGICAL 8-element column group;
// physical slot is g ^ (row & 7).
__device__ __forceinline__ int swz(int row, int g) {
    return row * 64 + (((g) ^ (row & 7)) << 3);
}
// async 16B global -> LDS (linear dest: wave-uniform base + lane*16)
__device__ __forceinline__ void gl_lds16(const short* g, short* l) {
    __builtin_amdgcn_global_load_lds(
        (const __attribute__((address_space(1))) void*)g,
        (__attribute__((address_space(3))) void*)l, 16, 0, 0);
}

// ---- transpose+downcast: fp32 src[R][C] -> bf16 dst[C][R], batched over z ---
__global__ __launch_bounds__(256) void transpose_k(const float* __restrict__ src,
                                                   short* __restrict__ dst,
                                                   int R, int C) {
    __shared__ __align__(16) short tile[64 * 65];
    int c0 = blockIdx.x * 64, r0 = blockIdx.y * 64;
    src += (size_t)blockIdx.z * R * C;
    dst += (size_t)blockIdx.z * R * C;
    int tid = threadIdx.x;
#pragma unroll
    for (int it = 0; it < 16; ++it) {
        int idx = it * 256 + tid;
        int rr = idx >> 6, cc = idx & 63;
        tile[cc * 65 + rr] = f2bf(src[(size_t)(r0 + rr) * C + c0 + cc]);
    }
    __syncthreads();
#pragma unroll
    for (int it = 0; it < 16; ++it) {
        int idx = it * 256 + tid;
        int cc = idx >> 6, rr = idx & 63;
        dst[(size_t)(c0 + cc) * R + r0 + rr] = tile[cc * 65 + rr];
    }
}

// ------ QKV projection + q/k norm: M=128 x N=128 (2 heads), 2-phase dbuf -----
// Grid (64, 24) = 1536 blocks = exactly 3 rounds at 2 blocks/CU (64 KB LDS).
// K-loop: STAGE(t+1) issued BEFORE COMPUTE(t), ONE __syncthreads per K-step.
// XT: [b][t][d] bf16 ; WT: [n][h*64+e][d] bf16
// Qw (pre-scaled by SCL), Kw: [bh][t][e] ; Vt: [bh][e][t]
__global__ __launch_bounds__(256, 2) void qkv_k(const short* __restrict__ XT,
                                                const short* __restrict__ WT,
                                                short* __restrict__ Qw,
                                                short* __restrict__ Kw,
                                                short* __restrict__ Vt) {
    __shared__ __align__(16) short ldsA[2][128 * 64];   // 2 x 16 KB, swizzled
    __shared__ __align__(16) short ldsB[2][128 * 64];   // 2 x 16 KB, swizzled
    int b  = blockIdx.x >> 4;                        // grid.x = 64: same-A blocks
    int t0 = (blockIdx.x & 15) * 128;                //   share XCD (x mod 8 const in y)
    int n  = blockIdx.y >> 3;
    int h0 = (blockIdx.y & 7) * 2;                   // 2 heads per block
    int tid = threadIdx.x, wave = tid >> 6, lane = tid & 63;
    int l15 = lane & 15, quad = lane >> 4;
    int wr = wave >> 1, wc = wave & 1;               // 2x2 wave grid

    const short* Arow = XT + ((size_t)b * T_SZ + t0) * DE;
    const short* Brow = WT + ((size_t)n * 1024 + h0 * 64) * DE;

    // per-lane pre-swizzle for global_load_lds staging
    int rA = lane >> 3;                   // row within the wave's 8-row stripe
    int gl = (lane & 7) ^ rA;             // logical column group for this slot

    float4v acc[4][4];
#pragma unroll
    for (int mm = 0; mm < 4; ++mm)
#pragma unroll
        for (int j = 0; j < 4; ++j) acc[mm][j] = zero4();

    auto STAGE = [&](short* La, short* Lb, int k0) {
#pragma unroll
        for (int it = 0; it < 4; ++it) {       // A,B: 128 rows, 8 rows/wave/issue
            int rowbase = it * 32 + wave * 8;
            gl_lds16(&Arow[(size_t)(rowbase + rA) * DE + k0 + gl * 8],
                     &La[(it * 256 + wave * 64) * 8]);
            gl_lds16(&Brow[(size_t)(rowbase + rA) * DE + k0 + gl * 8],
                     &Lb[(it * 256 + wave * 64) * 8]);
        }
    };
    auto COMPUTE = [&](const short* La, const short* Lb) {
#pragma unroll
        for (int ks = 0; ks < 2; ++ks) {
            short8 af[4], bf[4];
#pragma unroll
            for (int mm = 0; mm < 4; ++mm)
                af[mm] = *(const short8*)&La[swz(64 * wr + 16 * mm + l15, 4 * ks + quad)];
#pragma unroll
            for (int j = 0; j < 4; ++j)
                bf[j] = *(const short8*)&Lb[swz(64 * wc + 16 * j + l15, 4 * ks + quad)];
#pragma unroll
            for (int mm = 0; mm < 4; ++mm)
#pragma unroll
                for (int j = 0; j < 4; ++j)
                    acc[mm][j] = __builtin_amdgcn_mfma_f32_16x16x32_bf16(af[mm], bf[j], acc[mm][j], 0, 0, 0);
        }
    };

    STAGE(ldsA[0], ldsB[0], 0);
    __syncthreads();
    for (int k0 = 0; k0 < DE; k0 += 128) {     // 8 iters, 2 K-steps each
        STAGE(ldsA[1], ldsB[1], k0 + 64);      // k0+64 <= 960 always in-range
        COMPUTE(ldsA[0], ldsB[0]);
        __syncthreads();                       // drains prefetch + my ds_reads
        if (k0 + 128 < DE)
            STAGE(ldsA[0], ldsB[0], k0 + 128);
        COMPUTE(ldsA[1], ldsB[1]);
        __syncthreads();
    }

    // epilogue: wave owns one head (wc); per 16-row subtile mm
    int h = h0 + wc;
    int bh = b * NHEADS + h;
#pragma unroll
    for (int mm = 0; mm < 4; ++mm) {
        int tbase = t0 + 64 * wr + 16 * mm;
        if (n < 2) {
            float oscale = (n == 0) ? SCL : 1.0f;
            float mu[4], inv[4];
#pragma unroll
            for (int r = 0; r < 4; ++r) {
                float s1 = 0.f, s2 = 0.f;
#pragma unroll
                for (int jj = 0; jj < 4; ++jj) {
                    float v = acc[mm][jj][r];
                    s1 += v; s2 += v * v;
                }
                for (int sh = 1; sh < 16; sh <<= 1) {
                    s1 += __shfl_xor(s1, sh, 64);
                    s2 += __shfl_xor(s2, sh, 64);
                }
                mu[r] = s1 * (1.0f / 64.0f);
                float var = (s2 - 64.0f * mu[r] * mu[r]) * (1.0f / 63.0f);
                var = fmaxf(var, 0.0f);
                inv[r] = oscale / (sqrtf(var) + 1e-5f);
            }
            short* dst = (n == 0 ? Qw : Kw) + (size_t)bh * T_SZ * DH;
#pragma unroll
            for (int r = 0; r < 4; ++r) {
                int t = tbase + quad * 4 + r;
#pragma unroll
                for (int jj = 0; jj < 4; ++jj) {
                    float v = (acc[mm][jj][r] - mu[r]) * inv[r];
                    dst[(size_t)t * DH + 16 * jj + l15] = f2bf(v);
                }
            }
        } else {
#pragma unroll
            for (int r = 0; r < 4; ++r) {
                int t = tbase + quad * 4 + r;
#pragma unroll
                for (int jj = 0; jj < 4; ++jj) {
                    Vt[((size_t)bh * DH + 16 * jj + l15) * T_SZ + t] =
                        f2bf(acc[mm][jj][r]);
                }
            }
        }
    }
}

// -------- flash attention: 32x32 MFMA, P in-register, staged (round-6 base) --
// Round-7 falsified "staging is overhead": direct-global fragments = 266 us
// (per-lane 16B gathers at 128B stride = L1 transaction-bound). Staging stays.
// This round cuts the VALU pipe (51% busy, top pipe; ~17 us of it was the
// SOFTWARE bf16 rounding inside __float22bfloat162_rn):
//  - v_cvt_pk_bf16_f32 inline asm: 2 values / 1 instr, RNE in HW (T12/m240).
//  - l-sum moved to the 7%-busy MFMA pipe via ones-B mfma: olv has the SAME
//    C-layout as o, so normalization is a per-register divide — ldsL broadcast
//    and shfl_xor deleted. (l = sum of bf16-rounded P: consistent with PV's P.)
// Grid (bh=64, tq=16) = 1024 blocks = 4 blocks/CU = 4 waves/SIMD.
// Qw (pre-scaled), Kw: [bh][t][e] ; Vt: [bh][e][t]  (bf16) ; out: fp32 [b][h*64+e][t]
// |q.k*SCL| <= 11.4 -> exp2 never overflows; no max subtraction needed.
__global__ __launch_bounds__(256, 4) void attn_k(const short* __restrict__ Qw,
                                                 const short* __restrict__ Kw,
                                                 const short* __restrict__ Vt,
                                                 float* __restrict__ out) {
    __shared__ __align__(16) char smem[32768];
    short* ldsK = (short*)smem;                 // 2 bufs x [s][e] 64x64 swz (8 KB ea)
    short* ldsV = (short*)(smem + 16384);       // 2 bufs x [e][s] 64x64 swz

    int bh = blockIdx.x;
    int t0 = blockIdx.y * 128;
    int b = bh >> 4, h = bh & 15;
    int tid = threadIdx.x, wave = tid >> 6, lane = tid & 63;
    int l31 = lane & 31, b5 = lane >> 5;
    int tw = t0 + 32 * wave;                    // this wave's 32 q-rows

    const short* Qp = Qw + (size_t)bh * T_SZ * DH;
    const short* Kp = Kw + (size_t)bh * T_SZ * DH;
    const short* Vp = Vt + (size_t)bh * DH * T_SZ;

    // reg-staging lane geometry (LOGICAL column group; swz() applied at ds_write)
    int rA = lane >> 3;                // row within an 8-row stripe
    int g8 = lane & 7;

    // Q B-frags: qf[kk]: t = tw+l31, k = 16*kk+8*b5+e
    short8 qf[4];
#pragma unroll
    for (int kk = 0; kk < 4; ++kk)
        qf[kk] = *(const short8*)&Qp[(size_t)(tw + l31) * DH + 16 * kk + 8 * b5];

    const short one_bf = (short)0x3F80;         // bf16 1.0
    short8 ones = {one_bf, one_bf, one_bf, one_bf, one_bf, one_bf, one_bf, one_bf};

    f32x16 o0 = (f32x16)0.0f, o1 = (f32x16)0.0f;  // [etile]; C: row=t(regs), col=e(lane)
    f32x16 olv = (f32x16)0.0f;                    // l(t), same C-layout (ones-B mfma)

    short8 rk[2], rv[2];               // in-flight K/V tile (16 VGPR)
    auto LOADNEXT = [&](int s) {
#pragma unroll
        for (int it = 0; it < 2; ++it) {
            int row = 16 * wave + 8 * it + rA;
            rk[it] = *(const short8*)&Kp[(size_t)(s + row) * DH + g8 * 8];
            rv[it] = *(const short8*)&Vp[(size_t)row * T_SZ + s + g8 * 8];
        }
    };
    auto WRITESTAGE = [&](int buf) {
        short* Kb = ldsK + buf * 4096;
        short* Vb = ldsV + buf * 4096;
#pragma unroll
        for (int it = 0; it < 2; ++it) {
            int row = 16 * wave + 8 * it + rA;
            *(short8*)&Kb[swz(row, g8)] = rk[it];
            *(short8*)&Vb[swz(row, g8)] = rv[it];
        }
    };

    LOADNEXT(0);
    WRITESTAGE(0);
    __syncthreads();

    for (int s0 = 0; s0 < T_SZ; s0 += 64) {
        int cur = (s0 >> 6) & 1;
        LOADNEXT((s0 + 64) & (T_SZ - 1));          // flies under this tile's compute
        const short* Kc = ldsK + cur * 4096;
        const short* Vc = ldsV + cur * 4096;

        __builtin_amdgcn_s_setprio(1);

        // QK^T + exp2 + pack. z[r] = S^T[s_loc=32ss+(r&3)+8(r>>2)+4b5][t=tw+l31]
        uint2v u[2][4];   // [ssub][g]: dw0 = P(s=32ss+8g+4b5+{0,1}), dw1 = {2,3}
#pragma unroll
        for (int ss = 0; ss < 2; ++ss) {
            f32x16 z = (f32x16)0.0f;
#pragma unroll
            for (int kk = 0; kk < 4; ++kk) {
                // K A-frag: s_loc = 32*ss+l31, k = 16*kk+8*b5+e
                short8 ak = *(const short8*)&Kc[swz(32 * ss + l31, 2 * kk + b5)];
                z = __builtin_amdgcn_mfma_f32_32x32x16_bf16(ak, qf[kk], z, 0, 0, 0);
            }
#pragma unroll
            for (int g = 0; g < 4; ++g) {
                float p0 = __builtin_amdgcn_exp2f(z[4 * g + 0]);
                float p1 = __builtin_amdgcn_exp2f(z[4 * g + 1]);
                float p2 = __builtin_amdgcn_exp2f(z[4 * g + 2]);
                float p3 = __builtin_amdgcn_exp2f(z[4 * g + 3]);
                u[ss][g].x = cvt_pk_bf16(p0, p1);
                u[ss][g].y = cvt_pk_bf16(p2, p3);
            }
        }

        // PV: build pf[kks] in-register via permlane32_swap, then 3 MFMAs each
        // (o0, o1, and the ones-B l-sum). pf = P[t=own col][s=16kks+8b5+0..7]
        // (verified layout, rounds 5-6).
#pragma unroll
        for (int kks = 0; kks < 4; ++kks) {
            const int ssb = kks >> 1, ga = 2 * (kks & 1);
            unsigned a0 = u[ssb][ga].x,     a1 = u[ssb][ga].y;
            unsigned b0 = u[ssb][ga + 1].x, b1 = u[ssb][ga + 1].y;
            asm("v_permlane32_swap_b32 %0, %1" : "+v"(a0), "+v"(b0));
            asm("v_permlane32_swap_b32 %0, %1" : "+v"(a1), "+v"(b1));
            uint4v up; up.x = a0; up.y = a1; up.z = b0; up.w = b1;
            short8 pf = *(short8*)&up;
            // V B-frags: e = 32*et+l31, s_loc = 16*kks+8*b5+e'
            short8 v0 = *(const short8*)&Vc[swz(l31, 2 * kks + b5)];
            short8 v1 = *(const short8*)&Vc[swz(32 + l31, 2 * kks + b5)];
            o0  = __builtin_amdgcn_mfma_f32_32x32x16_bf16(pf, v0, o0, 0, 0, 0);
            o1  = __builtin_amdgcn_mfma_f32_32x32x16_bf16(pf, v1, o1, 0, 0, 0);
            olv = __builtin_amdgcn_mfma_f32_32x32x16_bf16(pf, ones, olv, 0, 0, 0);
        }

        __builtin_amdgcn_s_setprio(0);

        WRITESTAGE(cur ^ 1);    // vmcnt wait on rk/rv inserted here by compiler
        __syncthreads();        // next tile visible; cur reads done before t+2 overwrites
    }

    // epilogue: o/olv reg 4g+i is t = tw+8g+4b5+i, e = 32et+l31 -> float4 direct
#pragma unroll
    for (int g = 0; g < 4; ++g) {
        float4v ri;
#pragma unroll
        for (int i = 0; i < 4; ++i) ri[i] = 1.0f / olv[4 * g + i];
        float4v ov;
#pragma unroll
        for (int i = 0; i < 4; ++i) ov[i] = o0[4 * g + i] * ri[i];
        *(float4v*)&out[(size_t)(b * DE + h * DH + l31) * T_SZ
                        + tw + 8 * g + 4 * b5] = ov;
#pragma unroll
        for (int i = 0; i < 4; ++i) ov[i] = o1[4 * g + i] * ri[i];
        *(float4v*)&out[(size_t)(b * DE + h * DH + 32 + l31) * T_SZ
                        + tw + 8 * g + 4 * b5] = ov;
    }
}

extern "C" void kernel_launch(void* const* d_in, const int* in_sizes, int n_in,
                              void* d_out, int out_size, void* d_ws, size_t ws_size,
                              hipStream_t stream) {
    const float* x = (const float*)d_in[0];   // fp32 [B][D][T]
    const float* w = (const float*)d_in[1];   // fp32 [3][H][D][dh]
    float* out = (float*)d_out;               // fp32 [B][D][T]
    char* ws = (char*)d_ws;

    const size_t XT_BYTES = (size_t)B_SZ * T_SZ * DE * 2;       // 16.8 MB (bf16)
    const size_t WT_BYTES = (size_t)3 * NHEADS * DH * DE * 2;   // 6.3 MB
    const size_t QKV_BYTES = (size_t)BH * T_SZ * DH * 2;        // 16.8 MB each

    short* XT = (short*)(ws);
    short* WT = (short*)(ws + XT_BYTES);
    short* Qw = (short*)(ws + XT_BYTES + WT_BYTES);
    short* Kw = (short*)(ws + XT_BYTES + WT_BYTES + QKV_BYTES);
    short* Vt = (short*)(ws + XT_BYTES + WT_BYTES + 2 * QKV_BYTES);

    // x: per-b fp32 [D][T] -> bf16 XT [T][D]
    transpose_k<<<dim3(T_SZ / 64, DE / 64, B_SZ), 256, 0, stream>>>(x, XT, DE, T_SZ);
    // w: per-nh fp32 [D][dh] -> bf16 WT [nh][e][D]
    transpose_k<<<dim3(1, DE / 64, 3 * NHEADS), 256, 0, stream>>>(w, WT, DE, DH);
    qkv_k<<<dim3(64, 24), 256, 0, stream>>>(XT, WT, Qw, Kw, Vt);
    attn_k<<<dim3(BH, T_SZ / 128), 256, 0, stream>>>(Qw, Kw, Vt, out);
}